// Round 1
// baseline (4225.289 us; speedup 1.0000x reference)
//
#include <hip/hip_runtime.h>
#include <hip/hip_bf16.h>
#include <cstdint>
#include <cstddef>

#define N_    32
#define CIN_  64
#define T_    256
#define V_    25
#define S_    6400      // T_*V_
#define COUT_ 192
#define NTV_  204800    // N_*S_
#define EPS_  1e-5f

typedef unsigned short u16;

__device__ __forceinline__ float bf2f(u16 u) {
  uint32_t x = (uint32_t)u << 16;
  float f;
  __builtin_memcpy(&f, &x, 4);
  return f;
}
__device__ __forceinline__ u16 f2bf(float f) {
  uint32_t x;
  __builtin_memcpy(&x, &f, 4);
  uint32_t r = (x + 0x7FFFu + ((x >> 16) & 1u)) >> 16;
  return (u16)r;
}
__device__ __forceinline__ void store4bf(u16* p, float a, float b, float c, float d) {
  union { uint2 u; u16 s[4]; } pk;
  pk.s[0] = f2bf(a); pk.s[1] = f2bf(b); pk.s[2] = f2bf(c); pk.s[3] = f2bf(d);
  *(uint2*)p = pk.u;
}
__device__ __forceinline__ void load4bf(const u16* p, float* o) {
  union { uint2 u; u16 s[4]; } pk;
  pk.u = *(const uint2*)p;
  o[0] = bf2f(pk.s[0]); o[1] = bf2f(pk.s[1]); o[2] = bf2f(pk.s[2]); o[3] = bf2f(pk.s[3]);
}

__device__ __forceinline__ float loadv(const float* p, size_t i) { return p[i]; }
__device__ __forceinline__ float loadv(const u16* p, size_t i)   { return bf2f(p[i]); }

// -------- generic 1x1 conv: out[n,o,s] = sum_c W[o,c]*in[n,c,s] + bias[o]  (bf16 out)
// block: 256 thr, tile 64 o x 64 s. Optional per-channel sum/sumsq atomic stats (16 slots).
template<typename TIN, bool STATS>
__global__ __launch_bounds__(256) void k_conv1x1(
    const TIN* __restrict__ in, const float* __restrict__ W,
    const float* __restrict__ bias, u16* __restrict__ out,
    float* __restrict__ stSum, float* __restrict__ stSq,
    int O, int Cin)
{
  const int st = blockIdx.x;
  const int n  = st / 100;
  const int s0 = (st % 100) * 64;
  const int o0 = blockIdx.y * 64;
  const int tid = threadIdx.x;
  const int ty = tid >> 4, tx = tid & 15;

  __shared__ float Wt[16][68];
  __shared__ float Xt[16][68];

  float acc[4][4] = {};

  for (int c0 = 0; c0 < Cin; c0 += 16) {
    __syncthreads();
    for (int l = tid; l < 1024; l += 256) {
      const int kc = l >> 6, o = l & 63;
      const int oo = o0 + o;
      Wt[kc][o] = (oo < O) ? W[(size_t)oo * Cin + c0 + kc] : 0.f;
    }
    for (int l = tid; l < 1024; l += 256) {
      const int kc = l >> 6, sx = l & 63;
      Xt[kc][sx] = loadv(in, ((size_t)n * Cin + c0 + kc) * S_ + s0 + sx);
    }
    __syncthreads();
#pragma unroll
    for (int kc = 0; kc < 16; ++kc) {
      float a[4], b[4];
#pragma unroll
      for (int i = 0; i < 4; ++i) a[i] = Wt[kc][ty * 4 + i];
#pragma unroll
      for (int j = 0; j < 4; ++j) b[j] = Xt[kc][tx * 4 + j];
#pragma unroll
      for (int i = 0; i < 4; ++i)
#pragma unroll
        for (int j = 0; j < 4; ++j) acc[i][j] += a[i] * b[j];
    }
  }

#pragma unroll
  for (int i = 0; i < 4; ++i) {
    const int o = o0 + ty * 4 + i;
    if (o < O) {
      const float bv = bias[o];
      float v0 = acc[i][0] + bv, v1 = acc[i][1] + bv, v2 = acc[i][2] + bv, v3 = acc[i][3] + bv;
      store4bf(out + ((size_t)n * O + o) * S_ + s0 + tx * 4, v0, v1, v2, v3);
      if (STATS) {
        float ssum = v0 + v1 + v2 + v3;
        float ssq  = v0*v0 + v1*v1 + v2*v2 + v3*v3;
#pragma unroll
        for (int m = 1; m < 16; m <<= 1) {
          ssum += __shfl_xor(ssum, m);
          ssq  += __shfl_xor(ssq, m);
        }
        if (tx == 0) {
          const int slot = st & 15;
          atomicAdd(&stSum[o * 16 + slot], ssum);
          atomicAdd(&stSq[o * 16 + slot],  ssq);
        }
      }
    }
  }
}

// -------- temporal conv (k=KT taps along t, zero pad), Cin=192, O=64, writes tm channels [co0,co0+64)
template<int KT>
__global__ __launch_bounds__(256) void k_tconv(
    const u16* __restrict__ in, const float* __restrict__ W,
    const float* __restrict__ bias, u16* __restrict__ tm,
    float* __restrict__ stSum, float* __restrict__ stSq,
    int co0, int pad)
{
  const int st = blockIdx.x;
  const int n  = st / 100;
  const int s0 = (st % 100) * 64;
  const int tid = threadIdx.x;
  const int ty = tid >> 4, tx = tid & 15;
  __shared__ float Wt[16][68];
  __shared__ float Xt[16][68];
  float acc[4][4] = {};

  for (int tap = 0; tap < KT; ++tap) {
    const int dt = tap - pad;
    for (int c0 = 0; c0 < 192; c0 += 16) {
      __syncthreads();
      for (int l = tid; l < 1024; l += 256) {
        const int kc = l >> 6, o = l & 63;
        Wt[kc][o] = W[((size_t)o * 192 + c0 + kc) * KT + tap];
      }
      for (int l = tid; l < 1024; l += 256) {
        const int kc = l >> 6, sx = l & 63;
        const int ss = s0 + sx;
        const int tt = ss / 25 + dt;
        float v = 0.f;
        if (tt >= 0 && tt < T_) v = bf2f(in[((size_t)n * 192 + c0 + kc) * S_ + ss + dt * 25]);
        Xt[kc][sx] = v;
      }
      __syncthreads();
#pragma unroll
      for (int kc = 0; kc < 16; ++kc) {
        float a[4], b[4];
#pragma unroll
        for (int i = 0; i < 4; ++i) a[i] = Wt[kc][ty * 4 + i];
#pragma unroll
        for (int j = 0; j < 4; ++j) b[j] = Xt[kc][tx * 4 + j];
#pragma unroll
        for (int i = 0; i < 4; ++i)
#pragma unroll
          for (int j = 0; j < 4; ++j) acc[i][j] += a[i] * b[j];
      }
    }
  }

#pragma unroll
  for (int i = 0; i < 4; ++i) {
    const int ol = ty * 4 + i;
    const int o  = co0 + ol;
    const float bv = bias[ol];
    float v0 = acc[i][0] + bv, v1 = acc[i][1] + bv, v2 = acc[i][2] + bv, v3 = acc[i][3] + bv;
    store4bf(tm + ((size_t)n * 192 + o) * S_ + s0 + tx * 4, v0, v1, v2, v3);
    float ssum = v0 + v1 + v2 + v3;
    float ssq  = v0*v0 + v1*v1 + v2*v2 + v3*v3;
#pragma unroll
    for (int m = 1; m < 16; m <<= 1) { ssum += __shfl_xor(ssum, m); ssq += __shfl_xor(ssq, m); }
    if (tx == 0) {
      const int slot = st & 15;
      atomicAdd(&stSum[o * 16 + slot], ssum);
      atomicAdd(&stSq[o * 16 + slot],  ssq);
    }
  }
}

// -------- attention scores + softmax(+A+PA): one block per (n,k)
__global__ __launch_bounds__(256) void k_scores(
    const u16* __restrict__ fa, const u16* __restrict__ fb,
    const float* __restrict__ A, const float* __restrict__ PA,
    float* __restrict__ att)
{
  const int nk = blockIdx.x;
  const int n = nk / 3, k = nk % 3;
  __shared__ float sa[64][26];
  __shared__ float sb[64][26];
  __shared__ float sc[640];
  const int tid = threadIdx.x;
  const u16* fap = fa + ((size_t)n * 144 + k * 48) * S_;
  const u16* fbp = fb + ((size_t)n * 144 + k * 48) * S_;

  const int q0 = tid, q1 = tid + 256;
  const bool has2 = (tid + 512 < 625);
  const int q2 = has2 ? tid + 512 : 0;
  const int v0 = q0 / 25, w0 = q0 % 25;
  const int v1 = q1 / 25, w1 = q1 % 25;
  const int v2 = q2 / 25, w2 = q2 % 25;
  float a0 = 0.f, a1 = 0.f, a2 = 0.f;

  for (int ch = 0; ch < 192; ++ch) {      // 48 i x 4 t-chunks of 64
    const int i = ch >> 2, tb = (ch & 3) << 6;
    const size_t base = (size_t)i * S_ + (size_t)tb * 25;
    __syncthreads();
    for (int l = tid; l < 1600; l += 256) {
      sa[l / 25][l % 25] = bf2f(fap[base + l]);
      sb[l / 25][l % 25] = bf2f(fbp[base + l]);
    }
    __syncthreads();
#pragma unroll 8
    for (int r = 0; r < 64; ++r) {
      a0 += sa[r][v0] * sb[r][w0];
      a1 += sa[r][v1] * sb[r][w1];
      a2 += sa[r][v2] * sb[r][w2];
    }
  }
  __syncthreads();
  sc[q0] = a0;
  sc[q1] = a1;
  if (has2) sc[tid + 512] = a2;
  __syncthreads();
  if (tid < 25) {
    const int w = tid;
    const float scale = 1.f / 12288.f;
    float m = -1e30f;
    for (int v = 0; v < 25; ++v) m = fmaxf(m, sc[v * 25 + w]);
    m *= scale;
    float e[25], sum = 0.f;
#pragma unroll
    for (int v = 0; v < 25; ++v) { e[v] = __expf(sc[v * 25 + w] * scale - m); sum += e[v]; }
    const float inv = 1.f / sum;
    const float* Ak = A + k * 625;
    const float* Pk = PA + k * 625;
    float* ao = att + ((size_t)n * 3 + k) * 625;
#pragma unroll
    for (int v = 0; v < 25; ++v) ao[v * 25 + w] = e[v] * inv + Ak[v * 25 + w] + Pk[v * 25 + w];
  }
}

// -------- z[n, k*64+c, t*25+w] = sum_v x[n,c,t*25+v] * att[n,k,v,w]
__global__ __launch_bounds__(256) void k_z(
    const float* __restrict__ x, const float* __restrict__ att,
    u16* __restrict__ z)
{
  const int b = blockIdx.x;              // n*24 + k*8 + c8
  const int n = b / 24, r = b % 24, k = r / 8, c8 = r % 8;
  __shared__ float al[25][26];
  const int tid = threadIdx.x;
  for (int l = tid; l < 625; l += 256) al[l / 25][l % 25] = att[((size_t)n * 3 + k) * 625 + l];
  __syncthreads();
  for (int ci = 0; ci < 8; ++ci) {
    const int c = c8 * 8 + ci;
    const float* xp = x + ((size_t)n * 64 + c) * S_;
    u16* zp = z + ((size_t)n * 192 + k * 64 + c) * S_;
    for (int p = tid; p < S_; p += 256) {
      const int t = p / 25, w = p % 25;
      const float* xr = xp + t * 25;
      float acc = 0.f;
#pragma unroll
      for (int v = 0; v < 25; ++v) acc += xr[v] * al[v][w];
      zp[p] = f2bf(acc);
    }
  }
}

// -------- repack Wd[k,o,c] -> Wd2[o, k*64+c]; bd2[o] = sum_k bd[k,o]
__global__ void k_repack(const float* __restrict__ Wd, const float* __restrict__ bd,
                         float* __restrict__ Wd2, float* __restrict__ bd2)
{
  const int idx = blockIdx.x * 256 + threadIdx.x;
  if (idx < 192 * 192) {
    const int o = idx / 192, kc = idx % 192, k = kc / 64, c = kc % 64;
    Wd2[idx] = Wd[((size_t)k * 192 + o) * 64 + c];
  }
  if (idx < 192) bd2[idx] = bd[idx] + bd[192 + idx] + bd[384 + idx];
}

// -------- finalize BN: a = g*rsqrt(var+eps), c = b - a*mean
__global__ void k_bnparams(const float* __restrict__ sSum, const float* __restrict__ sSq,
                           const float* __restrict__ gamma, const float* __restrict__ beta,
                           float* __restrict__ a, float* __restrict__ c, int O)
{
  const int o = threadIdx.x + blockIdx.x * blockDim.x;
  if (o >= O) return;
  float sum = 0.f, sq = 0.f;
#pragma unroll
  for (int s = 0; s < 16; ++s) { sum += sSum[o * 16 + s]; sq += sSq[o * 16 + s]; }
  const float mean = sum * (1.f / NTV_);
  const float var  = sq  * (1.f / NTV_) - mean * mean;
  const float inv  = rsqrtf(var + EPS_);
  const float av = gamma[o] * inv;
  a[o] = av;
  c[o] = beta[o] - av * mean;
}

// -------- g = relu(bn_gcn(ypre) + bn_down(down))
__global__ __launch_bounds__(256) void k_g(
    const u16* __restrict__ ypre, const u16* __restrict__ down,
    const float* __restrict__ ga, const float* __restrict__ gc,
    const float* __restrict__ da, const float* __restrict__ dc,
    u16* __restrict__ g)
{
  const size_t i4 = (size_t)blockIdx.x * 256 + threadIdx.x;
  const int o = (int)((i4 / 1600) % 192);
  float yv[4], dv[4];
  load4bf(ypre + i4 * 4, yv);
  load4bf(down + i4 * 4, dv);
  const float A1 = ga[o], C1 = gc[o], A2 = da[o], C2 = dc[o];
  float r0 = fmaxf(A1 * yv[0] + C1 + A2 * dv[0] + C2, 0.f);
  float r1 = fmaxf(A1 * yv[1] + C1 + A2 * dv[1] + C2, 0.f);
  float r2 = fmaxf(A1 * yv[2] + C1 + A2 * dv[2] + C2, 0.f);
  float r3 = fmaxf(A1 * yv[3] + C1 + A2 * dv[3] + C2, 0.f);
  store4bf(g + i4 * 4, r0, r1, r2, r3);
}

// -------- out = relu(bn_tcn(tm) + bn_res(res))  (f32 output)
__global__ __launch_bounds__(256) void k_out(
    const u16* __restrict__ tm, const u16* __restrict__ resp,
    const float* __restrict__ ta, const float* __restrict__ tc,
    const float* __restrict__ ra, const float* __restrict__ rc,
    float* __restrict__ out)
{
  const size_t i4 = (size_t)blockIdx.x * 256 + threadIdx.x;
  const int o = (int)((i4 / 1600) % 192);
  float tv[4], rv[4];
  load4bf(tm + i4 * 4, tv);
  load4bf(resp + i4 * 4, rv);
  const float A1 = ta[o], C1 = tc[o], A2 = ra[o], C2 = rc[o];
  float4 ov;
  ov.x = fmaxf(A1 * tv[0] + C1 + A2 * rv[0] + C2, 0.f);
  ov.y = fmaxf(A1 * tv[1] + C1 + A2 * rv[1] + C2, 0.f);
  ov.z = fmaxf(A1 * tv[2] + C1 + A2 * rv[2] + C2, 0.f);
  ov.w = fmaxf(A1 * tv[3] + C1 + A2 * rv[3] + C2, 0.f);
  ((float4*)out)[i4] = ov;
}

extern "C" void kernel_launch(void* const* d_in, const int* in_sizes, int n_in,
                              void* d_out, int out_size, void* d_ws, size_t ws_size,
                              hipStream_t stream)
{
  const float* x      = (const float*)d_in[0];
  const float* A      = (const float*)d_in[1];
  const float* PA     = (const float*)d_in[2];
  const float* Wa     = (const float*)d_in[3];
  const float* ba     = (const float*)d_in[4];
  const float* Wb     = (const float*)d_in[5];
  const float* bb     = (const float*)d_in[6];
  const float* Wd     = (const float*)d_in[7];
  const float* bd     = (const float*)d_in[8];
  const float* gcng   = (const float*)d_in[9];
  const float* gcnb   = (const float*)d_in[10];
  const float* downw  = (const float*)d_in[11];
  const float* downbi = (const float*)d_in[12];
  const float* downg  = (const float*)d_in[13];
  const float* downb  = (const float*)d_in[14];
  const float* W11    = (const float*)d_in[15];
  const float* b11    = (const float*)d_in[16];
  const float* W21    = (const float*)d_in[17];
  const float* b21    = (const float*)d_in[18];
  const float* W31    = (const float*)d_in[19];
  const float* b31    = (const float*)d_in[20];
  const float* W12    = (const float*)d_in[21];
  const float* b12    = (const float*)d_in[22];
  const float* W22    = (const float*)d_in[23];
  const float* b22    = (const float*)d_in[24];
  const float* W32    = (const float*)d_in[25];
  const float* b32    = (const float*)d_in[26];
  const float* tcng   = (const float*)d_in[27];
  const float* tcnb   = (const float*)d_in[28];
  const float* resw   = (const float*)d_in[29];
  const float* resbi  = (const float*)d_in[30];
  const float* resg   = (const float*)d_in[31];
  const float* resb   = (const float*)d_in[32];
  (void)in_sizes; (void)n_in; (void)out_size; (void)ws_size;

  char* ws = (char*)d_ws;
  size_t off = 0;
  auto alloc = [&](size_t b) { size_t o = off; off += (b + 255) & ~(size_t)255; return o; };
  const size_t scratch_off = alloc(78643200);   // down_pre, later btmp
  const size_t g_off       = alloc(78643200);
  const size_t res_off     = alloc(78643200);
  const size_t tm_off      = alloc(78643200);
  const size_t att_off     = alloc(240000);
  const size_t wd2_off     = alloc(147456);
  const size_t bd2_off     = alloc(1024);
  const size_t slots_off   = alloc(4 * 2 * 192 * 16 * 4);
  const size_t bn_off      = alloc(8 * 192 * 4);

  // big intermediates overlaid inside d_out (dead by the time k_out writes):
  u16* fa   = (u16*)d_out;                 // [32,144,6400] bf16
  u16* fb   = fa + 29491200;
  u16* z    = (u16*)d_out;                 // [32,192,6400] bf16 (fa/fb dead)
  u16* ypre = z + 39321600;

  u16* down = (u16*)(ws + scratch_off);
  u16* btmp = (u16*)(ws + scratch_off);
  u16* g    = (u16*)(ws + g_off);
  u16* resp = (u16*)(ws + res_off);
  u16* tm   = (u16*)(ws + tm_off);
  float* att = (float*)(ws + att_off);
  float* Wd2 = (float*)(ws + wd2_off);
  float* bd2 = (float*)(ws + bd2_off);
  float* slots = (float*)(ws + slots_off);
  float* bnp   = (float*)(ws + bn_off);
  float* gcnSum = slots;          float* gcnSq = slots + 3072;
  float* dwnSum = slots + 6144;   float* dwnSq = slots + 9216;
  float* resSum = slots + 12288;  float* resSq = slots + 15360;
  float* tmSum  = slots + 18432;  float* tmSq  = slots + 21504;
  float* gcnA = bnp;         float* gcnC = bnp + 192;
  float* dwnA = bnp + 384;   float* dwnC = bnp + 576;
  float* resA = bnp + 768;   float* resC = bnp + 960;
  float* tmA  = bnp + 1152;  float* tmC  = bnp + 1344;

  hipMemsetAsync(slots, 0, 4 * 2 * 192 * 16 * 4, stream);

  const dim3 blk(256);
  const dim3 gconv(3200, 3);

  // ---- unit_gcn ----
  k_conv1x1<float,  false><<<gconv, blk, 0, stream>>>(x, Wa, ba, fa, nullptr, nullptr, 144, 64);
  k_conv1x1<float,  false><<<gconv, blk, 0, stream>>>(x, Wb, bb, fb, nullptr, nullptr, 144, 64);
  k_scores<<<dim3(96), blk, 0, stream>>>(fa, fb, A, PA, att);
  k_z<<<dim3(768), blk, 0, stream>>>(x, att, z);
  k_repack<<<dim3(144), blk, 0, stream>>>(Wd, bd, Wd2, bd2);
  k_conv1x1<u16, true><<<gconv, blk, 0, stream>>>(z, Wd2, bd2, ypre, gcnSum, gcnSq, 192, 192);
  k_conv1x1<float, true><<<gconv, blk, 0, stream>>>(x, downw, downbi, down, dwnSum, dwnSq, 192, 64);
  k_conv1x1<float, true><<<gconv, blk, 0, stream>>>(x, resw, resbi, resp, resSum, resSq, 192, 64);
  k_bnparams<<<dim3(1), dim3(192), 0, stream>>>(gcnSum, gcnSq, gcng, gcnb, gcnA, gcnC, 192);
  k_bnparams<<<dim3(1), dim3(192), 0, stream>>>(dwnSum, dwnSq, downg, downb, dwnA, dwnC, 192);
  k_bnparams<<<dim3(1), dim3(192), 0, stream>>>(resSum, resSq, resg, resb, resA, resC, 192);
  k_g<<<dim3(38400), blk, 0, stream>>>(ypre, down, gcnA, gcnC, dwnA, dwnC, g);

  // ---- unit_tcn_m: three (1x1 -> temporal conv) branches ----
  k_conv1x1<u16, false><<<gconv, blk, 0, stream>>>(g, W11, b11, btmp, nullptr, nullptr, 192, 192);
  k_tconv<1><<<dim3(3200), blk, 0, stream>>>(btmp, W12, b12, tm, tmSum, tmSq, 0, 0);
  k_conv1x1<u16, false><<<gconv, blk, 0, stream>>>(g, W21, b21, btmp, nullptr, nullptr, 192, 192);
  k_tconv<3><<<dim3(3200), blk, 0, stream>>>(btmp, W22, b22, tm, tmSum, tmSq, 64, 1);
  k_conv1x1<u16, false><<<gconv, blk, 0, stream>>>(g, W31, b31, btmp, nullptr, nullptr, 192, 192);
  k_tconv<7><<<dim3(3200), blk, 0, stream>>>(btmp, W32, b32, tm, tmSum, tmSq, 128, 3);
  k_bnparams<<<dim3(1), dim3(192), 0, stream>>>(tmSum, tmSq, tcng, tcnb, tmA, tmC, 192);

  // ---- final combine ----
  k_out<<<dim3(38400), blk, 0, stream>>>(tm, resp, tmA, tmC, resA, resC, (float*)d_out);
}

// Round 2
// 2466.621 us; speedup vs baseline: 1.7130x; 1.7130x over previous
//
#include <hip/hip_runtime.h>
#include <hip/hip_bf16.h>
#include <cstdint>
#include <cstddef>

#define EPS_  1e-5f
#define NTV_  204800

typedef unsigned short u16;
typedef __attribute__((ext_vector_type(8))) short short8;
typedef __attribute__((ext_vector_type(4))) float f32x4;

__device__ __forceinline__ float bf2f(u16 u) {
  uint32_t x = (uint32_t)u << 16;
  float f;
  __builtin_memcpy(&f, &x, 4);
  return f;
}
__device__ __forceinline__ u16 f2bf(float f) {
  uint32_t x;
  __builtin_memcpy(&x, &f, 4);
  uint32_t r = (x + 0x7FFFu + ((x >> 16) & 1u)) >> 16;
  return (u16)r;
}
__device__ __forceinline__ void load4bf(const u16* p, float* o) {
  union { uint2 u; u16 s[4]; } pk;
  pk.u = *(const uint2*)p;
  o[0] = bf2f(pk.s[0]); o[1] = bf2f(pk.s[1]); o[2] = bf2f(pk.s[2]); o[3] = bf2f(pk.s[3]);
}

// ---------------- weight convert/repack (f32 -> bf16, various layouts) ----------------
__global__ __launch_bounds__(256) void k_cvtw(
    const float* __restrict__ Wa, const float* __restrict__ Wb_,
    const float* __restrict__ dw, const float* __restrict__ rw,
    const float* __restrict__ W11, const float* __restrict__ W21, const float* __restrict__ W31,
    const float* __restrict__ Wd, const float* __restrict__ W12, const float* __restrict__ W22,
    const float* __restrict__ W32, const float* __restrict__ bd,
    u16* __restrict__ WB, float* __restrict__ bd2)
{
  int i = blockIdx.x * 256 + threadIdx.x;
  if (i < 9216) { WB[i] = f2bf(Wa[i]); return; }
  i -= 9216;
  if (i < 9216) { WB[9216 + i] = f2bf(Wb_[i]); return; }
  i -= 9216;
  if (i < 12288) { WB[18432 + i] = f2bf(dw[i]); return; }
  i -= 12288;
  if (i < 12288) { WB[30720 + i] = f2bf(rw[i]); return; }
  i -= 12288;
  if (i < 36864) { WB[43008 + i] = f2bf(W11[i]); return; }
  i -= 36864;
  if (i < 36864) { WB[79872 + i] = f2bf(W21[i]); return; }
  i -= 36864;
  if (i < 36864) { WB[116736 + i] = f2bf(W31[i]); return; }
  i -= 36864;
  if (i < 36864) {  // Wd [k,o,c] -> [o][k*64+c]
    const int o = i / 192, r = i % 192, k = r >> 6, c = r & 63;
    WB[153600 + i] = f2bf(Wd[((size_t)(k * 192 + o)) * 64 + c]);
    return;
  }
  i -= 36864;
  if (i < 12288) { WB[190464 + i] = f2bf(W12[i]); return; }
  i -= 12288;
  if (i < 36864) {  // W22 [o,c,3] -> [tap][o][c]
    const int tap = i / 12288, q = i % 12288, o = q / 192, c = q % 192;
    WB[202752 + i] = f2bf(W22[((size_t)(o * 192 + c)) * 3 + tap]);
    return;
  }
  i -= 36864;
  if (i < 86016) {  // W32 [o,c,7] -> [tap][o][c]
    const int tap = i / 12288, q = i % 12288, o = q / 192, c = q % 192;
    WB[239616 + i] = f2bf(W32[((size_t)(o * 192 + c)) * 7 + tap]);
    return;
  }
  i -= 86016;
  if (i < 192) bd2[i] = bd[i] + bd[192 + i] + bd[384 + i];
}

// ---------------- x [n,64,6400] f32 -> xb [n,6400,64] bf16 ----------------
__global__ __launch_bounds__(256) void k_xpose(const float* __restrict__ x, u16* __restrict__ xb)
{
  __shared__ u16 xt[256][72];
  const int bx = blockIdx.x;
  const int n = bx / 25, s0 = (bx % 25) * 256;
  const int tid = threadIdx.x;
  for (int l = tid; l < 64 * 64; l += 256) {
    const int c = l >> 6, q = l & 63;
    float4 v = *(const float4*)&x[((size_t)n * 64 + c) * 6400 + s0 + q * 4];
    xt[q * 4 + 0][c] = f2bf(v.x);
    xt[q * 4 + 1][c] = f2bf(v.y);
    xt[q * 4 + 2][c] = f2bf(v.z);
    xt[q * 4 + 3][c] = f2bf(v.w);
  }
  __syncthreads();
  for (int l = tid; l < 256 * 8; l += 256) {
    const int row = l >> 3, seg = l & 7;
    *(uint4*)&xb[((size_t)n * 6400 + s0 + row) * 64 + seg * 8] = *(const uint4*)&xt[row][seg * 8];
  }
}

// ---------------- MFMA conv / temporal-conv template ----------------
// in:  channels-last bf16 [n, 6400, C]
// Wb:  bf16 [KT][O][C]
// out: OUT_CF ? [n, Ostr, 6400] rows at o_off : [n, 6400, Ostr] cols at o_off
template<int C, int KT, int MF, bool OUT_CF, bool STATS>
__global__ __launch_bounds__(256) void k_conv(
    const u16* __restrict__ in, const u16* __restrict__ Wb,
    const float* __restrict__ bias, u16* __restrict__ out,
    float* __restrict__ stSum, float* __restrict__ stSq,
    int O, int Ostr, int o_off)
{
  constexpr int P = C + 8;
  constexpr int EPIP = MF * 16 + 8;
  constexpr int ASZ = MF * 16 * P;
  constexpr int ESZ = OUT_CF ? 0 : 4 * 64 * EPIP;
  constexpr int SMEM = ASZ > ESZ ? ASZ : ESZ;
  __shared__ u16 smem[SMEM];

  const int bx = blockIdx.x;
  const int n = bx / 25;
  const int s_blk = (bx % 25) * 256;
  const int o0 = blockIdx.y * (MF * 16);
  const int tid = threadIdx.x;
  const int w = tid >> 6;
  const int lane = tid & 63;
  const int lr = lane & 15, lg = lane >> 4;
  const int s_w = s_blk + w * 64;

  f32x4 acc[MF][4];
#pragma unroll
  for (int mi = 0; mi < MF; ++mi)
#pragma unroll
    for (int ni = 0; ni < 4; ++ni) {
      acc[mi][ni][0] = 0.f; acc[mi][ni][1] = 0.f; acc[mi][ni][2] = 0.f; acc[mi][ni][3] = 0.f;
    }

  for (int tap = 0; tap < KT; ++tap) {
    if (tap) __syncthreads();
    for (int l = tid; l < MF * 16 * (C / 8); l += 256) {
      const int o = l / (C / 8);
      const int cc = (l % (C / 8)) * 8;
      *(uint4*)&smem[o * P + cc] = *(const uint4*)&Wb[((size_t)(tap * O + o0 + o)) * C + cc];
    }
    __syncthreads();
    const int dt25 = (tap - KT / 2) * 25;
    const u16* bp[4];
    bool bok[4];
#pragma unroll
    for (int ni = 0; ni < 4; ++ni) {
      const int se = s_w + ni * 16 + lr + dt25;
      bok[ni] = (KT == 1) || ((unsigned)se < 6400u);
      bp[ni] = in + ((size_t)n * 6400 + se) * C + lg * 8;
    }
#pragma unroll
    for (int c0 = 0; c0 < C; c0 += 32) {
      short8 af[MF], bfv[4];
#pragma unroll
      for (int mi = 0; mi < MF; ++mi)
        af[mi] = *(const short8*)&smem[(mi * 16 + lr) * P + c0 + lg * 8];
#pragma unroll
      for (int ni = 0; ni < 4; ++ni) {
        short8 bv = {};
        if (bok[ni]) bv = *(const short8*)(bp[ni] + c0);
        bfv[ni] = bv;
      }
#pragma unroll
      for (int mi = 0; mi < MF; ++mi)
#pragma unroll
        for (int ni = 0; ni < 4; ++ni)
          acc[mi][ni] = __builtin_amdgcn_mfma_f32_16x16x32_bf16(af[mi], bfv[ni], acc[mi][ni], 0, 0, 0);
    }
  }

  // bias
#pragma unroll
  for (int mi = 0; mi < MF; ++mi) {
#pragma unroll
    for (int r = 0; r < 4; ++r) {
      const float bv = bias[o0 + mi * 16 + lg * 4 + r];
#pragma unroll
      for (int ni = 0; ni < 4; ++ni) acc[mi][ni][r] += bv;
    }
  }

  if (STATS) {
#pragma unroll
    for (int mi = 0; mi < MF; ++mi)
#pragma unroll
      for (int r = 0; r < 4; ++r) {
        float ss = acc[mi][0][r] + acc[mi][1][r] + acc[mi][2][r] + acc[mi][3][r];
        float sq = acc[mi][0][r] * acc[mi][0][r] + acc[mi][1][r] * acc[mi][1][r] +
                   acc[mi][2][r] * acc[mi][2][r] + acc[mi][3][r] * acc[mi][3][r];
#pragma unroll
        for (int m = 1; m < 16; m <<= 1) { ss += __shfl_xor(ss, m); sq += __shfl_xor(sq, m); }
        if (lr == 0) {
          const int og = o_off + o0 + mi * 16 + lg * 4 + r;
          const int slot = bx & 15;
          atomicAdd(&stSum[og * 16 + slot], ss);
          atomicAdd(&stSq[og * 16 + slot], sq);
        }
      }
  }

  if (OUT_CF) {
#pragma unroll
    for (int mi = 0; mi < MF; ++mi)
#pragma unroll
      for (int r = 0; r < 4; ++r) {
        const size_t rowb = ((size_t)n * Ostr + o_off + o0 + mi * 16 + lg * 4 + r) * 6400 + s_w + lr;
#pragma unroll
        for (int ni = 0; ni < 4; ++ni) out[rowb + ni * 16] = f2bf(acc[mi][ni][r]);
      }
  } else {
    __syncthreads();
    u16* e = smem + w * 64 * EPIP;
#pragma unroll
    for (int mi = 0; mi < MF; ++mi)
#pragma unroll
      for (int ni = 0; ni < 4; ++ni)
#pragma unroll
        for (int r = 0; r < 4; ++r)
          e[(ni * 16 + lr) * EPIP + mi * 16 + lg * 4 + r] = f2bf(acc[mi][ni][r]);
    __syncthreads();
    const u16* e2 = e + lane * EPIP;
    u16* dst = out + ((size_t)n * 6400 + s_w + lane) * Ostr + o_off + o0;
#pragma unroll
    for (int j = 0; j < MF * 2; ++j)
      *(uint4*)&dst[j * 8] = *(const uint4*)&e2[j * 8];
  }
}

// ---------------- attention scores + softmax(+A+PA): one block per (n,k) ----------------
__global__ __launch_bounds__(256) void k_scores(
    const u16* __restrict__ fa, const u16* __restrict__ fb,
    const float* __restrict__ A, const float* __restrict__ PA,
    float* __restrict__ att)
{
  const int nk = blockIdx.x;
  const int n = nk / 3, k = nk % 3;
  __shared__ float sa[64][26];
  __shared__ float sb[64][26];
  __shared__ float sc[640];
  const int tid = threadIdx.x;
  const u16* fap = fa + ((size_t)n * 144 + k * 48) * 6400;
  const u16* fbp = fb + ((size_t)n * 144 + k * 48) * 6400;

  const int q0 = tid, q1 = tid + 256;
  const bool has2 = (tid + 512 < 625);
  const int q2 = has2 ? tid + 512 : 0;
  const int v0 = q0 / 25, w0 = q0 % 25;
  const int v1 = q1 / 25, w1 = q1 % 25;
  const int v2 = q2 / 25, w2 = q2 % 25;
  float a0 = 0.f, a1 = 0.f, a2 = 0.f;

  for (int ch = 0; ch < 192; ++ch) {
    const int i = ch >> 2, tb = (ch & 3) << 6;
    const size_t base = (size_t)i * 6400 + (size_t)tb * 25;
    __syncthreads();
    for (int l = tid; l < 1600; l += 256) {
      sa[l / 25][l % 25] = bf2f(fap[base + l]);
      sb[l / 25][l % 25] = bf2f(fbp[base + l]);
    }
    __syncthreads();
#pragma unroll 8
    for (int r = 0; r < 64; ++r) {
      a0 += sa[r][v0] * sb[r][w0];
      a1 += sa[r][v1] * sb[r][w1];
      a2 += sa[r][v2] * sb[r][w2];
    }
  }
  __syncthreads();
  sc[q0] = a0;
  sc[q1] = a1;
  if (has2) sc[tid + 512] = a2;
  __syncthreads();
  if (tid < 25) {
    const int w = tid;
    const float scale = 1.f / 12288.f;
    float m = -1e30f;
    for (int v = 0; v < 25; ++v) m = fmaxf(m, sc[v * 25 + w]);
    m *= scale;
    float e[25], sum = 0.f;
#pragma unroll
    for (int v = 0; v < 25; ++v) { e[v] = __expf(sc[v * 25 + w] * scale - m); sum += e[v]; }
    const float inv = 1.f / sum;
    const float* Ak = A + k * 625;
    const float* Pk = PA + k * 625;
    float* ao = att + ((size_t)n * 3 + k) * 625;
#pragma unroll
    for (int v = 0; v < 25; ++v) ao[v * 25 + w] = e[v] * inv + Ak[v * 25 + w] + Pk[v * 25 + w];
  }
}

// ---------------- z[n, t*25+w, k*64+c] = sum_v xb[n, t*25+v, c] * att[n,k,v,w] ----------------
__global__ __launch_bounds__(256) void k_z(
    const u16* __restrict__ xb, const float* __restrict__ att, u16* __restrict__ z)
{
  __shared__ float attl[1950];   // [3k][25v][26 pitch]
  __shared__ u16 xt[12800];      // [8t*25v][64c]
  const int bx = blockIdx.x;
  const int n = bx >> 5, t0 = (bx & 31) * 8;
  const int tid = threadIdx.x;

  for (int l = tid; l < 1875; l += 256) {
    const int k = l / 625, vw = l % 625, v = vw / 25, w = vw % 25;
    attl[(k * 25 + v) * 26 + w] = att[((size_t)n * 3 + k) * 625 + vw];
  }
  for (int l = tid; l < 200 * 8; l += 256) {
    const int row = l >> 3, seg = l & 7;
    *(uint4*)&xt[row * 64 + seg * 8] =
        *(const uint4*)&xb[((size_t)n * 6400 + t0 * 25 + row) * 64 + seg * 8];
  }
  __syncthreads();

  for (int it = 0; it < 19; ++it) {
    const int l = tid + it * 256;
    if (l >= 4800) break;
    const int hi = l >> 6, lo = l & 63;
    const int k = hi / 25, w = hi % 25;
    const int tl = lo >> 3, c0 = (lo & 7) * 8;
    float accv[8] = {};
    for (int v = 0; v < 25; ++v) {
      const float aw = attl[(k * 25 + v) * 26 + w];
      union { uint4 u; u16 s[8]; } xv;
      xv.u = *(const uint4*)&xt[(tl * 25 + v) * 64 + c0];
#pragma unroll
      for (int j = 0; j < 8; ++j) accv[j] += aw * bf2f(xv.s[j]);
    }
    union { uint4 u; u16 s[8]; } ov;
#pragma unroll
    for (int j = 0; j < 8; ++j) ov.s[j] = f2bf(accv[j]);
    *(uint4*)&z[((size_t)n * 6400 + (t0 + tl) * 25 + w) * 192 + k * 64 + c0] = ov.u;
  }
}

// ---------------- BN finalize ----------------
__global__ void k_bnparams(const float* __restrict__ sSum, const float* __restrict__ sSq,
                           const float* __restrict__ gamma, const float* __restrict__ beta,
                           float* __restrict__ a, float* __restrict__ c, int O)
{
  const int o = threadIdx.x + blockIdx.x * blockDim.x;
  if (o >= O) return;
  float sum = 0.f, sq = 0.f;
#pragma unroll
  for (int s = 0; s < 16; ++s) { sum += sSum[o * 16 + s]; sq += sSq[o * 16 + s]; }
  const float mean = sum * (1.f / NTV_);
  const float var = sq * (1.f / NTV_) - mean * mean;
  const float inv = rsqrtf(var + EPS_);
  const float av = gamma[o] * inv;
  a[o] = av;
  c[o] = beta[o] - av * mean;
}

// ---------------- g = relu(bn(ypre) + bn(down)), CF in -> CL out ----------------
__global__ __launch_bounds__(256) void k_g(
    const u16* __restrict__ ypre, const u16* __restrict__ down,
    const float* __restrict__ ga, const float* __restrict__ gc,
    const float* __restrict__ da, const float* __restrict__ dc,
    u16* __restrict__ g)
{
  __shared__ u16 gl[64][200];
  const int bx = blockIdx.x;
  const int n = bx / 100, s0 = (bx % 100) * 64;
  const int tid = threadIdx.x;
  for (int l = tid; l < 192 * 8; l += 256) {
    const int c = l >> 3, sx0 = (l & 7) * 8;
    union { uint4 u; u16 s[8]; } yv, dv;
    yv.u = *(const uint4*)&ypre[((size_t)n * 192 + c) * 6400 + s0 + sx0];
    dv.u = *(const uint4*)&down[((size_t)n * 192 + c) * 6400 + s0 + sx0];
    const float A1 = ga[c], C1 = gc[c], A2 = da[c], C2 = dc[c];
#pragma unroll
    for (int j = 0; j < 8; ++j) {
      const float v = fmaxf(A1 * bf2f(yv.s[j]) + C1 + A2 * bf2f(dv.s[j]) + C2, 0.f);
      gl[sx0 + j][c] = f2bf(v);
    }
  }
  __syncthreads();
  for (int l = tid; l < 64 * 24; l += 256) {
    const int s = l / 24, seg = l % 24;
    *(uint4*)&g[((size_t)n * 6400 + s0 + s) * 192 + seg * 8] = *(const uint4*)&gl[s][seg * 8];
  }
}

// ---------------- out = relu(bn_tcn(tm) + bn_res(res)) (f32, CF) ----------------
__global__ __launch_bounds__(256) void k_out(
    const u16* __restrict__ tm, const u16* __restrict__ resp,
    const float* __restrict__ ta, const float* __restrict__ tc,
    const float* __restrict__ ra, const float* __restrict__ rc,
    float* __restrict__ out)
{
  const size_t i4 = (size_t)blockIdx.x * 256 + threadIdx.x;
  const int o = (int)((i4 / 1600) % 192);
  float tv[4], rv[4];
  load4bf(tm + i4 * 4, tv);
  load4bf(resp + i4 * 4, rv);
  const float A1 = ta[o], C1 = tc[o], A2 = ra[o], C2 = rc[o];
  float4 ov;
  ov.x = fmaxf(A1 * tv[0] + C1 + A2 * rv[0] + C2, 0.f);
  ov.y = fmaxf(A1 * tv[1] + C1 + A2 * rv[1] + C2, 0.f);
  ov.z = fmaxf(A1 * tv[2] + C1 + A2 * rv[2] + C2, 0.f);
  ov.w = fmaxf(A1 * tv[3] + C1 + A2 * rv[3] + C2, 0.f);
  ((float4*)out)[i4] = ov;
}

extern "C" void kernel_launch(void* const* d_in, const int* in_sizes, int n_in,
                              void* d_out, int out_size, void* d_ws, size_t ws_size,
                              hipStream_t stream)
{
  const float* x      = (const float*)d_in[0];
  const float* A      = (const float*)d_in[1];
  const float* PA     = (const float*)d_in[2];
  const float* Wa     = (const float*)d_in[3];
  const float* ba     = (const float*)d_in[4];
  const float* Wb     = (const float*)d_in[5];
  const float* bb     = (const float*)d_in[6];
  const float* Wd     = (const float*)d_in[7];
  const float* bd     = (const float*)d_in[8];
  const float* gcng   = (const float*)d_in[9];
  const float* gcnb   = (const float*)d_in[10];
  const float* downw  = (const float*)d_in[11];
  const float* downbi = (const float*)d_in[12];
  const float* downg  = (const float*)d_in[13];
  const float* downb  = (const float*)d_in[14];
  const float* W11    = (const float*)d_in[15];
  const float* b11    = (const float*)d_in[16];
  const float* W21    = (const float*)d_in[17];
  const float* b21    = (const float*)d_in[18];
  const float* W31    = (const float*)d_in[19];
  const float* b31    = (const float*)d_in[20];
  const float* W12    = (const float*)d_in[21];
  const float* b12    = (const float*)d_in[22];
  const float* W22    = (const float*)d_in[23];
  const float* b22    = (const float*)d_in[24];
  const float* W32    = (const float*)d_in[25];
  const float* b32    = (const float*)d_in[26];
  const float* tcng   = (const float*)d_in[27];
  const float* tcnb   = (const float*)d_in[28];
  const float* resw   = (const float*)d_in[29];
  const float* resbi  = (const float*)d_in[30];
  const float* resg   = (const float*)d_in[31];
  const float* resb   = (const float*)d_in[32];
  (void)in_sizes; (void)n_in; (void)out_size; (void)ws_size;

  // ---- d_out overlay (all dead before k_out writes) ----
  u16* ob = (u16*)d_out;
  u16* fa = ob;                       // [32,144,6400] bf16 CF
  u16* fb = ob + 29491200;            // [32,144,6400]
  u16* xb = ob + 58982400;            // [32,6400,64] bf16 CL
  float* att = (float*)(ob + 72089600);        // 60000 f32
  u16*  WB   = ob + 72209600;                   // 325632 u16 of bf16 weights
  float* bd2 = (float*)(ob + 72535232);        // 192 f32
  float* slots = (float*)(ob + 72535616);      // 24576 f32
  float* gcnSum = slots;           float* gcnSq = slots + 3072;
  float* dwnSum = slots + 6144;    float* dwnSq = slots + 9216;
  float* resSum = slots + 12288;   float* resSq = slots + 15360;
  float* tmSum  = slots + 18432;   float* tmSq  = slots + 21504;

  // ---- ws: 4 big slots + bn params (bnp must survive into k_out) ----
  char* ws = (char*)d_ws;
  const size_t SLOT = 78643200;
  u16* z    = (u16*)(ws);             // later g
  u16* g    = (u16*)(ws);
  u16* ypre = (u16*)(ws + SLOT);      // later btmp
  u16* btmp = (u16*)(ws + SLOT);
  u16* down = (u16*)(ws + 2 * SLOT);  // later tm
  u16* tm   = (u16*)(ws + 2 * SLOT);
  u16* resp = (u16*)(ws + 3 * SLOT);
  float* bnp = (float*)(ws + 4 * SLOT);
  float* gcnA = bnp;          float* gcnC = bnp + 192;
  float* dwnA = bnp + 384;    float* dwnC = bnp + 576;
  float* resA = bnp + 768;    float* resC = bnp + 960;
  float* tmA  = bnp + 1152;   float* tmC  = bnp + 1344;

  hipMemsetAsync(slots, 0, 24576 * 4, stream);

  const dim3 blk(256);

  k_cvtw<<<dim3(1273), blk, 0, stream>>>(Wa, Wb, downw, resw, W11, W21, W31,
                                         Wd, W12, W22, W32, bd, WB, bd2);
  k_xpose<<<dim3(800), blk, 0, stream>>>(x, xb);

  // ---- unit_gcn ----
  k_conv<64, 1, 3, true, false><<<dim3(800, 3), blk, 0, stream>>>(
      xb, WB + 0, ba, fa, nullptr, nullptr, 144, 144, 0);
  k_conv<64, 1, 3, true, false><<<dim3(800, 3), blk, 0, stream>>>(
      xb, WB + 9216, bb, fb, nullptr, nullptr, 144, 144, 0);
  k_scores<<<dim3(96), blk, 0, stream>>>(fa, fb, A, PA, att);
  k_z<<<dim3(1024), blk, 0, stream>>>(xb, att, z);
  k_conv<192, 1, 4, true, true><<<dim3(800, 3), blk, 0, stream>>>(
      z, WB + 153600, bd2, ypre, gcnSum, gcnSq, 192, 192, 0);
  k_conv<64, 1, 4, true, true><<<dim3(800, 3), blk, 0, stream>>>(
      xb, WB + 18432, downbi, down, dwnSum, dwnSq, 192, 192, 0);
  k_conv<64, 1, 4, true, true><<<dim3(800, 3), blk, 0, stream>>>(
      xb, WB + 30720, resbi, resp, resSum, resSq, 192, 192, 0);
  k_bnparams<<<dim3(1), dim3(192), 0, stream>>>(gcnSum, gcnSq, gcng, gcnb, gcnA, gcnC, 192);
  k_bnparams<<<dim3(1), dim3(192), 0, stream>>>(dwnSum, dwnSq, downg, downb, dwnA, dwnC, 192);
  k_bnparams<<<dim3(1), dim3(192), 0, stream>>>(resSum, resSq, resg, resb, resA, resC, 192);
  k_g<<<dim3(3200), blk, 0, stream>>>(ypre, down, gcnA, gcnC, dwnA, dwnC, g);

  // ---- unit_tcn_m ----
  k_conv<192, 1, 4, false, false><<<dim3(800, 3), blk, 0, stream>>>(
      g, WB + 43008, b11, btmp, nullptr, nullptr, 192, 192, 0);
  k_conv<192, 1, 4, true, true><<<dim3(800, 1), blk, 0, stream>>>(
      btmp, WB + 190464, b12, tm, tmSum, tmSq, 64, 192, 0);
  k_conv<192, 1, 4, false, false><<<dim3(800, 3), blk, 0, stream>>>(
      g, WB + 79872, b21, btmp, nullptr, nullptr, 192, 192, 0);
  k_conv<192, 3, 4, true, true><<<dim3(800, 1), blk, 0, stream>>>(
      btmp, WB + 202752, b22, tm, tmSum, tmSq, 64, 192, 64);
  k_conv<192, 1, 4, false, false><<<dim3(800, 3), blk, 0, stream>>>(
      g, WB + 116736, b31, btmp, nullptr, nullptr, 192, 192, 0);
  k_conv<192, 7, 4, true, true><<<dim3(800, 1), blk, 0, stream>>>(
      btmp, WB + 239616, b32, tm, tmSum, tmSq, 64, 192, 128);
  k_bnparams<<<dim3(1), dim3(192), 0, stream>>>(tmSum, tmSq, tcng, tcnb, tmA, tmC, 192);

  // ---- final combine ----
  k_out<<<dim3(38400), blk, 0, stream>>>(tm, resp, tmA, tmC, resA, resC, (float*)d_out);
}

// Round 3
// 1800.852 us; speedup vs baseline: 2.3463x; 1.3697x over previous
//
#include <hip/hip_runtime.h>
#include <hip/hip_bf16.h>
#include <cstdint>
#include <cstddef>

#define EPS_  1e-5f
#define NTV_  204800

typedef unsigned short u16;
typedef __attribute__((ext_vector_type(8))) short short8;
typedef __attribute__((ext_vector_type(4))) float f32x4;

__device__ __forceinline__ float bf2f(u16 u) {
  uint32_t x = (uint32_t)u << 16;
  float f;
  __builtin_memcpy(&f, &x, 4);
  return f;
}
__device__ __forceinline__ u16 f2bf(float f) {
  uint32_t x;
  __builtin_memcpy(&x, &f, 4);
  uint32_t r = (x + 0x7FFFu + ((x >> 16) & 1u)) >> 16;
  return (u16)r;
}
__device__ __forceinline__ void load4bf(const u16* p, float* o) {
  union { uint2 u; u16 s[4]; } pk;
  pk.u = *(const uint2*)p;
  o[0] = bf2f(pk.s[0]); o[1] = bf2f(pk.s[1]); o[2] = bf2f(pk.s[2]); o[3] = bf2f(pk.s[3]);
}

// ---------------- weight convert/repack (f32 -> bf16, various layouts) ----------------
__global__ __launch_bounds__(256) void k_cvtw(
    const float* __restrict__ Wa, const float* __restrict__ Wb_,
    const float* __restrict__ dw, const float* __restrict__ rw,
    const float* __restrict__ W11, const float* __restrict__ W21, const float* __restrict__ W31,
    const float* __restrict__ Wd, const float* __restrict__ W12, const float* __restrict__ W22,
    const float* __restrict__ W32, const float* __restrict__ bd,
    u16* __restrict__ WB, float* __restrict__ bd2)
{
  int i = blockIdx.x * 256 + threadIdx.x;
  if (i < 9216) { WB[i] = f2bf(Wa[i]); return; }
  i -= 9216;
  if (i < 9216) { WB[9216 + i] = f2bf(Wb_[i]); return; }
  i -= 9216;
  if (i < 12288) { WB[18432 + i] = f2bf(dw[i]); return; }
  i -= 12288;
  if (i < 12288) { WB[30720 + i] = f2bf(rw[i]); return; }
  i -= 12288;
  if (i < 36864) { WB[43008 + i] = f2bf(W11[i]); return; }
  i -= 36864;
  if (i < 36864) { WB[79872 + i] = f2bf(W21[i]); return; }
  i -= 36864;
  if (i < 36864) { WB[116736 + i] = f2bf(W31[i]); return; }
  i -= 36864;
  if (i < 36864) {  // Wd [k,o,c] -> [o][k*64+c]
    const int o = i / 192, r = i % 192, k = r >> 6, c = r & 63;
    WB[153600 + i] = f2bf(Wd[((size_t)(k * 192 + o)) * 64 + c]);
    return;
  }
  i -= 36864;
  if (i < 12288) { WB[190464 + i] = f2bf(W12[i]); return; }
  i -= 12288;
  if (i < 36864) {  // W22 [o,c,3] -> [tap][o][c]
    const int tap = i / 12288, q = i % 12288, o = q / 192, c = q % 192;
    WB[202752 + i] = f2bf(W22[((size_t)(o * 192 + c)) * 3 + tap]);
    return;
  }
  i -= 36864;
  if (i < 86016) {  // W32 [o,c,7] -> [tap][o][c]
    const int tap = i / 12288, q = i % 12288, o = q / 192, c = q % 192;
    WB[239616 + i] = f2bf(W32[((size_t)(o * 192 + c)) * 7 + tap]);
    return;
  }
  i -= 86016;
  if (i < 192) bd2[i] = bd[i] + bd[192 + i] + bd[384 + i];
}

// ---------------- x [n,64,6400] f32 -> xb [n,6400,64] bf16 ----------------
__global__ __launch_bounds__(256) void k_xpose(const float* __restrict__ x, u16* __restrict__ xb)
{
  __shared__ u16 xt[256][72];
  const int bx = blockIdx.x;
  const int n = bx / 25, s0 = (bx % 25) * 256;
  const int tid = threadIdx.x;
  for (int l = tid; l < 64 * 64; l += 256) {
    const int c = l >> 6, q = l & 63;
    float4 v = *(const float4*)&x[((size_t)n * 64 + c) * 6400 + s0 + q * 4];
    xt[q * 4 + 0][c] = f2bf(v.x);
    xt[q * 4 + 1][c] = f2bf(v.y);
    xt[q * 4 + 2][c] = f2bf(v.z);
    xt[q * 4 + 3][c] = f2bf(v.w);
  }
  __syncthreads();
  for (int l = tid; l < 256 * 8; l += 256) {
    const int row = l >> 3, seg = l & 7;
    *(uint4*)&xb[((size_t)n * 6400 + s0 + row) * 64 + seg * 8] = *(const uint4*)&xt[row][seg * 8];
  }
}

// ---------------- MFMA conv / temporal-conv template ----------------
// in:  channels-last bf16 [n, 6400, C]
// Wb:  bf16 [KT][O][C]
// out: OUT_CF ? [n, Ostr, 6400] rows at o_off : [n, 6400, Ostr] cols at o_off
template<int C, int KT, int MF, bool OUT_CF, bool STATS>
__global__ __launch_bounds__(256) void k_conv(
    const u16* __restrict__ in, const u16* __restrict__ Wb,
    const float* __restrict__ bias, u16* __restrict__ out,
    float* __restrict__ stSum, float* __restrict__ stSq,
    int O, int Ostr, int o_off)
{
  constexpr int P = C + 8;
  constexpr int EPIP = MF * 16 + 8;
  constexpr int ASZ = MF * 16 * P;
  constexpr int ESZ = OUT_CF ? 0 : 4 * 64 * EPIP;
  constexpr int SMEM = ASZ > ESZ ? ASZ : ESZ;
  __shared__ u16 smem[SMEM];

  const int bx = blockIdx.x;
  const int n = bx / 25;
  const int s_blk = (bx % 25) * 256;
  const int o0 = blockIdx.y * (MF * 16);
  const int tid = threadIdx.x;
  const int w = tid >> 6;
  const int lane = tid & 63;
  const int lr = lane & 15, lg = lane >> 4;
  const int s_w = s_blk + w * 64;

  f32x4 acc[MF][4];
#pragma unroll
  for (int mi = 0; mi < MF; ++mi)
#pragma unroll
    for (int ni = 0; ni < 4; ++ni) {
      acc[mi][ni][0] = 0.f; acc[mi][ni][1] = 0.f; acc[mi][ni][2] = 0.f; acc[mi][ni][3] = 0.f;
    }

  for (int tap = 0; tap < KT; ++tap) {
    if (tap) __syncthreads();
    for (int l = tid; l < MF * 16 * (C / 8); l += 256) {
      const int o = l / (C / 8);
      const int cc = (l % (C / 8)) * 8;
      *(uint4*)&smem[o * P + cc] = *(const uint4*)&Wb[((size_t)(tap * O + o0 + o)) * C + cc];
    }
    __syncthreads();
    const int dt25 = (tap - KT / 2) * 25;
    const u16* bp[4];
    bool bok[4];
#pragma unroll
    for (int ni = 0; ni < 4; ++ni) {
      const int se = s_w + ni * 16 + lr + dt25;
      bok[ni] = (KT == 1) || ((unsigned)se < 6400u);
      bp[ni] = in + ((size_t)n * 6400 + se) * C + lg * 8;
    }
#pragma unroll
    for (int c0 = 0; c0 < C; c0 += 32) {
      short8 af[MF], bfv[4];
#pragma unroll
      for (int mi = 0; mi < MF; ++mi)
        af[mi] = *(const short8*)&smem[(mi * 16 + lr) * P + c0 + lg * 8];
#pragma unroll
      for (int ni = 0; ni < 4; ++ni) {
        short8 bv = {};
        if (bok[ni]) bv = *(const short8*)(bp[ni] + c0);
        bfv[ni] = bv;
      }
#pragma unroll
      for (int mi = 0; mi < MF; ++mi)
#pragma unroll
        for (int ni = 0; ni < 4; ++ni)
          acc[mi][ni] = __builtin_amdgcn_mfma_f32_16x16x32_bf16(af[mi], bfv[ni], acc[mi][ni], 0, 0, 0);
    }
  }

  // bias
#pragma unroll
  for (int mi = 0; mi < MF; ++mi) {
#pragma unroll
    for (int r = 0; r < 4; ++r) {
      const float bv = bias[o0 + mi * 16 + lg * 4 + r];
#pragma unroll
      for (int ni = 0; ni < 4; ++ni) acc[mi][ni][r] += bv;
    }
  }

  if (STATS) {
#pragma unroll
    for (int mi = 0; mi < MF; ++mi)
#pragma unroll
      for (int r = 0; r < 4; ++r) {
        float ss = acc[mi][0][r] + acc[mi][1][r] + acc[mi][2][r] + acc[mi][3][r];
        float sq = acc[mi][0][r] * acc[mi][0][r] + acc[mi][1][r] * acc[mi][1][r] +
                   acc[mi][2][r] * acc[mi][2][r] + acc[mi][3][r] * acc[mi][3][r];
#pragma unroll
        for (int m = 1; m < 16; m <<= 1) { ss += __shfl_xor(ss, m); sq += __shfl_xor(sq, m); }
        if (lr == 0) {
          const int og = o_off + o0 + mi * 16 + lg * 4 + r;
          const int slot = bx & 15;
          atomicAdd(&stSum[og * 16 + slot], ss);
          atomicAdd(&stSq[og * 16 + slot], sq);
        }
      }
  }

  if (OUT_CF) {
#pragma unroll
    for (int mi = 0; mi < MF; ++mi)
#pragma unroll
      for (int r = 0; r < 4; ++r) {
        const size_t rowb = ((size_t)n * Ostr + o_off + o0 + mi * 16 + lg * 4 + r) * 6400 + s_w + lr;
#pragma unroll
        for (int ni = 0; ni < 4; ++ni) out[rowb + ni * 16] = f2bf(acc[mi][ni][r]);
      }
  } else {
    __syncthreads();
    u16* e = smem + w * 64 * EPIP;
#pragma unroll
    for (int mi = 0; mi < MF; ++mi)
#pragma unroll
      for (int ni = 0; ni < 4; ++ni)
#pragma unroll
        for (int r = 0; r < 4; ++r)
          e[(ni * 16 + lr) * EPIP + mi * 16 + lg * 4 + r] = f2bf(acc[mi][ni][r]);
    __syncthreads();
    const u16* e2 = e + lane * EPIP;
    u16* dst = out + ((size_t)n * 6400 + s_w + lane) * Ostr + o_off + o0;
#pragma unroll
    for (int j = 0; j < MF * 2; ++j)
      *(uint4*)&dst[j * 8] = *(const uint4*)&e2[j * 8];
  }
}

// ---------------- attention scores, partial reduction ----------------
// part[(nk*24+seg)*640 + v*25+w] = sum_{ch in seg, t} fa[ch][t*25+v]*fb[ch][t*25+w]
__global__ __launch_bounds__(256) void k_scores_part(
    const u16* __restrict__ fa, const u16* __restrict__ fb, float* __restrict__ part)
{
  const int nk = blockIdx.x;   // 96
  const int seg = blockIdx.y;  // 24
  const int n = nk / 3, k = nk % 3;
  __shared__ u16 sa[2 * 6400];
  __shared__ u16 sb[2 * 6400];
  const int tid = threadIdx.x;
  const u16* fap = fa + ((size_t)(n * 144 + k * 48 + seg * 2)) * 6400;
  const u16* fbp = fb + ((size_t)(n * 144 + k * 48 + seg * 2)) * 6400;
  for (int l = tid; l < 1600; l += 256) {
    ((uint4*)sa)[l] = ((const uint4*)fap)[l];
    ((uint4*)sb)[l] = ((const uint4*)fbp)[l];
  }
  __syncthreads();

  const int l0 = tid, l1 = tid + 256, l2 = tid + 512;
  const bool ok2 = l2 < 625;
  const int v0 = l0 / 25, w0 = l0 % 25;
  const int v1 = l1 / 25, w1 = l1 % 25;
  const int v2 = ok2 ? l2 / 25 : 0, w2 = ok2 ? l2 % 25 : 0;
  float a0 = 0.f, a1 = 0.f, a2 = 0.f;

  for (int t = 0; t < 256; ++t) {
    const int base = t * 25;
#pragma unroll
    for (int ch = 0; ch < 2; ++ch) {
      const u16* sar = sa + ch * 6400 + base;
      const u16* sbr = sb + ch * 6400 + base;
      a0 += bf2f(sar[v0]) * bf2f(sbr[w0]);
      a1 += bf2f(sar[v1]) * bf2f(sbr[w1]);
      a2 += bf2f(sar[v2]) * bf2f(sbr[w2]);
    }
  }
  float* po = part + ((size_t)nk * 24 + seg) * 640;
  po[l0] = a0;
  po[l1] = a1;
  if (ok2) po[l2] = a2;
}

// ---------------- reduce partials + softmax(+A+PA) ----------------
__global__ __launch_bounds__(256) void k_softmax(
    const float* __restrict__ part, const float* __restrict__ A,
    const float* __restrict__ PA, float* __restrict__ att)
{
  const int nk = blockIdx.x;
  const int n = nk / 3, k = nk % 3;
  __shared__ float sc[640];
  const int tid = threadIdx.x;
  const float* pb = part + (size_t)nk * 24 * 640;
  for (int l = tid; l < 625; l += 256) {
    float s = 0.f;
#pragma unroll
    for (int seg = 0; seg < 24; ++seg) s += pb[seg * 640 + l];
    sc[l] = s;
  }
  __syncthreads();
  if (tid < 25) {
    const int w = tid;
    const float scale = 1.f / 12288.f;
    float m = -1e30f;
    for (int v = 0; v < 25; ++v) m = fmaxf(m, sc[v * 25 + w]);
    m *= scale;
    float e[25], sum = 0.f;
#pragma unroll
    for (int v = 0; v < 25; ++v) { e[v] = __expf(sc[v * 25 + w] * scale - m); sum += e[v]; }
    const float inv = 1.f / sum;
    const float* Ak = A + k * 625;
    const float* Pk = PA + k * 625;
    float* ao = att + ((size_t)n * 3 + k) * 625;
#pragma unroll
    for (int v = 0; v < 25; ++v) ao[v * 25 + w] = e[v] * inv + Ak[v * 25 + w] + Pk[v * 25 + w];
  }
}

// ---------------- z[n, t*25+w, k*64+c] = sum_v xb[n, t*25+v, c] * att[n,k,v,w] ----------------
__global__ __launch_bounds__(256) void k_z(
    const u16* __restrict__ xb, const float* __restrict__ att, u16* __restrict__ z)
{
  __shared__ float attl[1950];   // [3k][25v][26 pitch]
  __shared__ u16 xt[12800];      // [8t*25v][64c]
  const int bx = blockIdx.x;
  const int n = bx >> 5, t0 = (bx & 31) * 8;
  const int tid = threadIdx.x;

  for (int l = tid; l < 1875; l += 256) {
    const int k = l / 625, vw = l % 625, v = vw / 25, w = vw % 25;
    attl[(k * 25 + v) * 26 + w] = att[((size_t)n * 3 + k) * 625 + vw];
  }
  for (int l = tid; l < 200 * 8; l += 256) {
    const int row = l >> 3, seg = l & 7;
    *(uint4*)&xt[row * 64 + seg * 8] =
        *(const uint4*)&xb[((size_t)n * 6400 + t0 * 25 + row) * 64 + seg * 8];
  }
  __syncthreads();

  for (int it = 0; it < 19; ++it) {
    const int l = tid + it * 256;
    if (l >= 4800) break;
    const int hi = l >> 6, lo = l & 63;
    const int k = hi / 25, w = hi % 25;
    const int tl = lo >> 3, c0 = (lo & 7) * 8;
    float accv[8] = {};
    for (int v = 0; v < 25; ++v) {
      const float aw = attl[(k * 25 + v) * 26 + w];
      union { uint4 u; u16 s[8]; } xv;
      xv.u = *(const uint4*)&xt[(tl * 25 + v) * 64 + c0];
#pragma unroll
      for (int j = 0; j < 8; ++j) accv[j] += aw * bf2f(xv.s[j]);
    }
    union { uint4 u; u16 s[8]; } ov;
#pragma unroll
    for (int j = 0; j < 8; ++j) ov.s[j] = f2bf(accv[j]);
    *(uint4*)&z[((size_t)n * 6400 + (t0 + tl) * 25 + w) * 192 + k * 64 + c0] = ov.u;
  }
}

// ---------------- BN finalize ----------------
__global__ void k_bnparams(const float* __restrict__ sSum, const float* __restrict__ sSq,
                           const float* __restrict__ gamma, const float* __restrict__ beta,
                           float* __restrict__ a, float* __restrict__ c, int O)
{
  const int o = threadIdx.x + blockIdx.x * blockDim.x;
  if (o >= O) return;
  float sum = 0.f, sq = 0.f;
#pragma unroll
  for (int s = 0; s < 16; ++s) { sum += sSum[o * 16 + s]; sq += sSq[o * 16 + s]; }
  const float mean = sum * (1.f / NTV_);
  const float var = sq * (1.f / NTV_) - mean * mean;
  const float inv = rsqrtf(var + EPS_);
  const float av = gamma[o] * inv;
  a[o] = av;
  c[o] = beta[o] - av * mean;
}

// ---------------- g = relu(bn(ypre) + bn(down)), CF in -> CL out ----------------
__global__ __launch_bounds__(256) void k_g(
    const u16* __restrict__ ypre, const u16* __restrict__ down,
    const float* __restrict__ ga, const float* __restrict__ gc,
    const float* __restrict__ da, const float* __restrict__ dc,
    u16* __restrict__ g)
{
  __shared__ u16 gl[64][200];
  const int bx = blockIdx.x;
  const int n = bx / 100, s0 = (bx % 100) * 64;
  const int tid = threadIdx.x;
  for (int l = tid; l < 192 * 8; l += 256) {
    const int c = l >> 3, sx0 = (l & 7) * 8;
    union { uint4 u; u16 s[8]; } yv, dv;
    yv.u = *(const uint4*)&ypre[((size_t)n * 192 + c) * 6400 + s0 + sx0];
    dv.u = *(const uint4*)&down[((size_t)n * 192 + c) * 6400 + s0 + sx0];
    const float A1 = ga[c], C1 = gc[c], A2 = da[c], C2 = dc[c];
#pragma unroll
    for (int j = 0; j < 8; ++j) {
      const float v = fmaxf(A1 * bf2f(yv.s[j]) + C1 + A2 * bf2f(dv.s[j]) + C2, 0.f);
      gl[sx0 + j][c] = f2bf(v);
    }
  }
  __syncthreads();
  for (int l = tid; l < 64 * 24; l += 256) {
    const int s = l / 24, seg = l % 24;
    *(uint4*)&g[((size_t)n * 6400 + s0 + s) * 192 + seg * 8] = *(const uint4*)&gl[s][seg * 8];
  }
}

// ---------------- out = relu(bn_tcn(tm) + bn_res(res)) (f32, CF) ----------------
__global__ __launch_bounds__(256) void k_out(
    const u16* __restrict__ tm, const u16* __restrict__ resp,
    const float* __restrict__ ta, const float* __restrict__ tc,
    const float* __restrict__ ra, const float* __restrict__ rc,
    float* __restrict__ out)
{
  const size_t i4 = (size_t)blockIdx.x * 256 + threadIdx.x;
  const int o = (int)((i4 / 1600) % 192);
  float tv[4], rv[4];
  load4bf(tm + i4 * 4, tv);
  load4bf(resp + i4 * 4, rv);
  const float A1 = ta[o], C1 = tc[o], A2 = ra[o], C2 = rc[o];
  float4 ov;
  ov.x = fmaxf(A1 * tv[0] + C1 + A2 * rv[0] + C2, 0.f);
  ov.y = fmaxf(A1 * tv[1] + C1 + A2 * rv[1] + C2, 0.f);
  ov.z = fmaxf(A1 * tv[2] + C1 + A2 * rv[2] + C2, 0.f);
  ov.w = fmaxf(A1 * tv[3] + C1 + A2 * rv[3] + C2, 0.f);
  ((float4*)out)[i4] = ov;
}

extern "C" void kernel_launch(void* const* d_in, const int* in_sizes, int n_in,
                              void* d_out, int out_size, void* d_ws, size_t ws_size,
                              hipStream_t stream)
{
  const float* x      = (const float*)d_in[0];
  const float* A      = (const float*)d_in[1];
  const float* PA     = (const float*)d_in[2];
  const float* Wa     = (const float*)d_in[3];
  const float* ba     = (const float*)d_in[4];
  const float* Wb     = (const float*)d_in[5];
  const float* bb     = (const float*)d_in[6];
  const float* Wd     = (const float*)d_in[7];
  const float* bd     = (const float*)d_in[8];
  const float* gcng   = (const float*)d_in[9];
  const float* gcnb   = (const float*)d_in[10];
  const float* downw  = (const float*)d_in[11];
  const float* downbi = (const float*)d_in[12];
  const float* downg  = (const float*)d_in[13];
  const float* downb  = (const float*)d_in[14];
  const float* W11    = (const float*)d_in[15];
  const float* b11    = (const float*)d_in[16];
  const float* W21    = (const float*)d_in[17];
  const float* b21    = (const float*)d_in[18];
  const float* W31    = (const float*)d_in[19];
  const float* b31    = (const float*)d_in[20];
  const float* W12    = (const float*)d_in[21];
  const float* b12    = (const float*)d_in[22];
  const float* W22    = (const float*)d_in[23];
  const float* b22    = (const float*)d_in[24];
  const float* W32    = (const float*)d_in[25];
  const float* b32    = (const float*)d_in[26];
  const float* tcng   = (const float*)d_in[27];
  const float* tcnb   = (const float*)d_in[28];
  const float* resw   = (const float*)d_in[29];
  const float* resbi  = (const float*)d_in[30];
  const float* resg   = (const float*)d_in[31];
  const float* resb   = (const float*)d_in[32];
  (void)in_sizes; (void)n_in; (void)out_size; (void)ws_size;

  // ---- d_out overlay (all dead before k_out writes) ----
  u16* ob = (u16*)d_out;
  u16* fa = ob;                       // [32,144,6400] bf16 CF
  u16* fb = ob + 29491200;            // [32,144,6400]
  u16* xb = ob + 58982400;            // [32,6400,64] bf16 CL
  float* att = (float*)(ob + 72089600);        // 60000 f32
  u16*  WB   = ob + 72209600;                   // 325632 u16 of bf16 weights
  float* bd2 = (float*)(ob + 72535232);        // 192 f32
  float* slots = (float*)(ob + 72535616);      // 24576 f32, ends at u16 72584768
  float* part  = (float*)(ob + 72584768);      // 96*24*640 f32 = 2949120 u16
  float* gcnSum = slots;           float* gcnSq = slots + 3072;
  float* dwnSum = slots + 6144;    float* dwnSq = slots + 9216;
  float* resSum = slots + 12288;   float* resSq = slots + 15360;
  float* tmSum  = slots + 18432;   float* tmSq  = slots + 21504;

  // ---- ws: 4 big slots + bn params (bnp must survive into k_out) ----
  char* ws = (char*)d_ws;
  const size_t SLOT = 78643200;
  u16* z    = (u16*)(ws);             // later g
  u16* g    = (u16*)(ws);
  u16* ypre = (u16*)(ws + SLOT);      // later btmp
  u16* btmp = (u16*)(ws + SLOT);
  u16* down = (u16*)(ws + 2 * SLOT);  // later tm
  u16* tm   = (u16*)(ws + 2 * SLOT);
  u16* resp = (u16*)(ws + 3 * SLOT);
  float* bnp = (float*)(ws + 4 * SLOT);
  float* gcnA = bnp;          float* gcnC = bnp + 192;
  float* dwnA = bnp + 384;    float* dwnC = bnp + 576;
  float* resA = bnp + 768;    float* resC = bnp + 960;
  float* tmA  = bnp + 1152;   float* tmC  = bnp + 1344;

  hipMemsetAsync(slots, 0, 24576 * 4, stream);

  const dim3 blk(256);

  k_cvtw<<<dim3(1273), blk, 0, stream>>>(Wa, Wb, downw, resw, W11, W21, W31,
                                         Wd, W12, W22, W32, bd, WB, bd2);
  k_xpose<<<dim3(800), blk, 0, stream>>>(x, xb);

  // ---- unit_gcn ----
  k_conv<64, 1, 3, true, false><<<dim3(800, 3), blk, 0, stream>>>(
      xb, WB + 0, ba, fa, nullptr, nullptr, 144, 144, 0);
  k_conv<64, 1, 3, true, false><<<dim3(800, 3), blk, 0, stream>>>(
      xb, WB + 9216, bb, fb, nullptr, nullptr, 144, 144, 0);
  k_scores_part<<<dim3(96, 24), blk, 0, stream>>>(fa, fb, part);
  k_softmax<<<dim3(96), blk, 0, stream>>>(part, A, PA, att);
  k_z<<<dim3(1024), blk, 0, stream>>>(xb, att, z);
  k_conv<192, 1, 4, true, true><<<dim3(800, 3), blk, 0, stream>>>(
      z, WB + 153600, bd2, ypre, gcnSum, gcnSq, 192, 192, 0);
  k_conv<64, 1, 4, true, true><<<dim3(800, 3), blk, 0, stream>>>(
      xb, WB + 18432, downbi, down, dwnSum, dwnSq, 192, 192, 0);
  k_conv<64, 1, 4, true, true><<<dim3(800, 3), blk, 0, stream>>>(
      xb, WB + 30720, resbi, resp, resSum, resSq, 192, 192, 0);
  k_bnparams<<<dim3(1), dim3(192), 0, stream>>>(gcnSum, gcnSq, gcng, gcnb, gcnA, gcnC, 192);
  k_bnparams<<<dim3(1), dim3(192), 0, stream>>>(dwnSum, dwnSq, downg, downb, dwnA, dwnC, 192);
  k_bnparams<<<dim3(1), dim3(192), 0, stream>>>(resSum, resSq, resg, resb, resA, resC, 192);
  k_g<<<dim3(3200), blk, 0, stream>>>(ypre, down, gcnA, gcnC, dwnA, dwnC, g);

  // ---- unit_tcn_m ----
  k_conv<192, 1, 4, false, false><<<dim3(800, 3), blk, 0, stream>>>(
      g, WB + 43008, b11, btmp, nullptr, nullptr, 192, 192, 0);
  k_conv<192, 1, 4, true, true><<<dim3(800, 1), blk, 0, stream>>>(
      btmp, WB + 190464, b12, tm, tmSum, tmSq, 64, 192, 0);
  k_conv<192, 1, 4, false, false><<<dim3(800, 3), blk, 0, stream>>>(
      g, WB + 79872, b21, btmp, nullptr, nullptr, 192, 192, 0);
  k_conv<192, 3, 4, true, true><<<dim3(800, 1), blk, 0, stream>>>(
      btmp, WB + 202752, b22, tm, tmSum, tmSq, 64, 192, 64);
  k_conv<192, 1, 4, false, false><<<dim3(800, 3), blk, 0, stream>>>(
      g, WB + 116736, b31, btmp, nullptr, nullptr, 192, 192, 0);
  k_conv<192, 7, 4, true, true><<<dim3(800, 1), blk, 0, stream>>>(
      btmp, WB + 239616, b32, tm, tmSum, tmSq, 64, 192, 128);
  k_bnparams<<<dim3(1), dim3(192), 0, stream>>>(tmSum, tmSq, tcng, tcnb, tmA, tmC, 192);

  // ---- final combine ----
  k_out<<<dim3(38400), blk, 0, stream>>>(tm, resp, tmA, tmC, resA, resC, (float*)d_out);
}